// Round 11
// baseline (267.207 us; speedup 1.0000x reference)
//
#include <hip/hip_runtime.h>
#include <hip/hip_bf16.h>

#define T_TOK 2048
#define HID 1024
#define FFNDIM 2048
#define NEXP 8

typedef __attribute__((ext_vector_type(8))) short short8;
typedef __attribute__((ext_vector_type(4))) float f32x4;

__device__ inline unsigned short f2bf(float f) {
  union { float f; unsigned int u; } v; v.f = f;
  unsigned int u = v.u;
  unsigned int r = (u + 0x7fffu + ((u >> 16) & 1u)) >> 16;
  return (unsigned short)r;
}

__device__ inline short8 pack8(float4 a, float4 b) {
  union { __hip_bfloat162 h2[4]; short8 s; } u;
  u.h2[0] = __float22bfloat162_rn(float2{a.x, a.y});
  u.h2[1] = __float22bfloat162_rn(float2{a.z, a.w});
  u.h2[2] = __float22bfloat162_rn(float2{b.x, b.y});
  u.h2[3] = __float22bfloat162_rn(float2{b.z, b.w});
  return u.s;
}

// ---------------- router ----------------
__global__ __launch_bounds__(256) void router_kernel(
    const float* __restrict__ x, const float* __restrict__ gw,
    int* __restrict__ counts, int* __restrict__ top_i, float* __restrict__ top_w) {
  int lane = threadIdx.x & 63;
  int t = blockIdx.x * 4 + (threadIdx.x >> 6);
  if (t >= T_TOK) return;
  float xv[16];
#pragma unroll
  for (int i = 0; i < 16; ++i) xv[i] = x[(size_t)t * HID + i * 64 + lane];
  float logit[NEXP];
#pragma unroll
  for (int e = 0; e < NEXP; ++e) {
    float s = 0.f;
#pragma unroll
    for (int i = 0; i < 16; ++i) s += xv[i] * gw[e * HID + i * 64 + lane];
#pragma unroll
    for (int off = 32; off > 0; off >>= 1) s += __shfl_xor(s, off);
    logit[e] = s;
  }
  if (lane == 0) {
    float mx = logit[0];
#pragma unroll
    for (int e = 1; e < NEXP; ++e) mx = fmaxf(mx, logit[e]);
    float p[NEXP]; float sum = 0.f;
#pragma unroll
    for (int e = 0; e < NEXP; ++e) { p[e] = expf(logit[e] - mx); sum += p[e]; }
#pragma unroll
    for (int e = 0; e < NEXP; ++e) p[e] /= sum;
    int i0 = 0;
#pragma unroll
    for (int e = 1; e < NEXP; ++e) if (p[e] > p[i0]) i0 = e;
    int i1 = (i0 == 0) ? 1 : 0;
#pragma unroll
    for (int e = 0; e < NEXP; ++e) if (e != i0 && p[e] > p[i1]) i1 = e;
    float w0 = p[i0], w1v = p[i1];
    float s2 = w0 + w1v;
    w0 /= s2; w1v /= s2;
    top_i[t * 2 + 0] = i0; top_i[t * 2 + 1] = i1;
    top_w[t * 2 + 0] = w0; top_w[t * 2 + 1] = w1v;
    atomicAdd(&counts[i0], 1);
    atomicAdd(&counts[i1], 1);
  }
}

__global__ void offsets_kernel(const int* __restrict__ counts, int* __restrict__ offsets) {
  if (threadIdx.x == 0 && blockIdx.x == 0) {
    int s = 0;
    for (int e = 0; e < NEXP; ++e) { offsets[e] = s; s += counts[e]; }
    offsets[NEXP] = s;
  }
}

__global__ __launch_bounds__(256) void scatter_kernel(
    const int* __restrict__ top_i, const float* __restrict__ top_w,
    const int* __restrict__ offsets, int* __restrict__ cursor,
    int* __restrict__ row_tok, int* __restrict__ tok_rows) {
  int t = blockIdx.x * 256 + threadIdx.x;
  if (t >= T_TOK) return;
#pragma unroll
  for (int k = 0; k < 2; ++k) {
    int e = top_i[t * 2 + k];
    int p = atomicAdd(&cursor[e], 1);
    int idx = offsets[e] + p;
    row_tok[idx] = t;
    tok_rows[t * 2 + k] = idx;
  }
}

__global__ __launch_bounds__(256) void gather_kernel(
    const float* __restrict__ x, const int* __restrict__ row_tok,
    unsigned short* __restrict__ Xg) {
  int r = blockIdx.x;
  int t = row_tok[r];
  int c = threadIdx.x * 4;
  float4 v = *reinterpret_cast<const float4*>(x + (size_t)t * HID + c);
  ushort4 o;
  o.x = f2bf(v.x); o.y = f2bf(v.y); o.z = f2bf(v.z); o.w = f2bf(v.w);
  *reinterpret_cast<ushort4*>(Xg + (size_t)r * HID + c) = o;
}

// ======== GEMM1 weights-resident: block = (expert, 32 ffn-cols) ========
// B LDS [64][1024] bf16 (rows 0-31 = w1 cols, 32-63 = w3 cols), converted once.
// A direct-from-global per-lane dwordx4. No barriers in main loop; 8 independent
// waves each stream 64-token tiles (2-deep named A prefetch).
__global__ __launch_bounds__(512) void gemm1_wr(
    const unsigned short* __restrict__ Xg,
    const float* __restrict__ w1, const float* __restrict__ w3,
    const int* __restrict__ counts, const int* __restrict__ offsets,
    unsigned short* __restrict__ hbuf) {
  extern __shared__ unsigned short sB1[];   // 64*1024 bf16 = 128 KB
  int e = blockIdx.z;
  int cnt = counts[e];
  if (cnt == 0) return;
  int off = offsets[e];
  int ntb = blockIdx.x * 32;

  int tid = threadIdx.x, lane = tid & 63, wid = tid >> 6;
  int fr = lane & 15, fq = lane >> 4;

  // ---- B init: 64 rows x 1024 K; 8 threads/row, 256B-contiguous per row-group ----
  {
    int brow = tid >> 3;          // 0..63
    int sub = tid & 7;
    const float* src = (brow < 32)
        ? (w1 + ((size_t)e * FFNDIM + ntb + brow) * HID)
        : (w3 + ((size_t)e * FFNDIM + ntb + (brow - 32)) * HID);
    int swz = brow & 7;
#pragma unroll
    for (int i = 0; i < 16; ++i) {
      int g = sub + i * 8;        // granule of 8 elems
      float4 a = *reinterpret_cast<const float4*>(src + g * 8);
      float4 b = *reinterpret_cast<const float4*>(src + g * 8 + 4);
      *reinterpret_cast<short8*>(&sB1[brow * 1024 + ((g ^ swz) << 3)]) = pack8(a, b);
    }
  }
  __syncthreads();

  // ---- per-wave independent token-tile stream ----
  for (int tix = wid; tix * 64 < cnt; tix += 8) {
    const unsigned short* Xb[4];
#pragma unroll
    for (int mf = 0; mf < 4; ++mf) {
      int r = tix * 64 + mf * 16 + fr;
      if (r > cnt - 1) r = cnt - 1;
      Xb[mf] = Xg + (size_t)(off + r) * HID + fq * 8;
    }

    f32x4 acc[4][4];
#pragma unroll
    for (int mf = 0; mf < 4; ++mf)
#pragma unroll
      for (int nf = 0; nf < 4; ++nf) acc[mf][nf] = (f32x4){0.f, 0.f, 0.f, 0.f};

    short8 p0[4], p1[4];
#define ALOAD1(P, T)                                                        \
    do {                                                                    \
      _Pragma("unroll")                                                     \
      for (int mf = 0; mf < 4; ++mf)                                        \
        P[mf] = *reinterpret_cast<const short8*>(Xb[mf] + (T) * 32);        \
    } while (0)
#define COMP1(P, T)                                                         \
    do {                                                                    \
      short8 bfr[4];                                                        \
      _Pragma("unroll")                                                     \
      for (int nf = 0; nf < 4; ++nf) {                                      \
        int row = (nf < 2) ? (nf * 16 + fr) : (32 + (nf - 2) * 16 + fr);    \
        int g = (T) * 4 + fq;                                               \
        bfr[nf] = *reinterpret_cast<const short8*>(                         \
            &sB1[row * 1024 + ((g ^ (row & 7)) << 3)]);                     \
      }                                                                     \
      __builtin_amdgcn_s_setprio(1);                                        \
      _Pragma("unroll")                                                     \
      for (int mf = 0; mf < 4; ++mf)                                        \
        _Pragma("unroll")                                                   \
        for (int nf = 0; nf < 4; ++nf)                                      \
          acc[mf][nf] = __builtin_amdgcn_mfma_f32_16x16x32_bf16(            \
              P[mf], bfr[nf], acc[mf][nf], 0, 0, 0);                        \
      __builtin_amdgcn_s_setprio(0);                                        \
    } while (0)

    ALOAD1(p0, 0);
    ALOAD1(p1, 1);
    for (int t = 0; t < 32; t += 2) {
      COMP1(p0, t);
      if (t + 2 < 32) ALOAD1(p0, t + 2);
      COMP1(p1, t + 1);
      if (t + 3 < 32) ALOAD1(p1, t + 3);
    }
#undef ALOAD1
#undef COMP1

    // epilogue: SwiGLU -> hbuf bf16
#pragma unroll
    for (int mf = 0; mf < 4; ++mf) {
      int rl = tix * 64 + mf * 16 + fq * 4;
#pragma unroll
      for (int jj = 0; jj < 4; ++jj) {
        int gm = rl + jj;
        if (gm < cnt) {
#pragma unroll
          for (int nf = 0; nf < 2; ++nf) {
            float h1 = acc[mf][nf][jj];
            float h3 = acc[mf][nf + 2][jj];
            float sv = h1 / (1.f + expf(-h1)) * h3;
            hbuf[(size_t)(off + gm) * FFNDIM + ntb + nf * 16 + fr] = f2bf(sv);
          }
        }
      }
    }
  }
}

// ======== GEMM2 weights-resident: block = (expert, 32 hid-cols) ========
// B LDS [32][2048] bf16 (w2 cols), converted once. Full K in-block (no split-K).
__global__ __launch_bounds__(512) void gemm2_wr(
    const unsigned short* __restrict__ hbuf, const float* __restrict__ w2,
    const int* __restrict__ counts, const int* __restrict__ offsets,
    float* __restrict__ Yg) {
  extern __shared__ unsigned short sB2[];   // 32*2048 bf16 = 128 KB
  int e = blockIdx.z;
  int cnt = counts[e];
  if (cnt == 0) return;
  int off = offsets[e];
  int ntb = blockIdx.x * 32;

  int tid = threadIdx.x, lane = tid & 63, wid = tid >> 6;
  int fr = lane & 15, fq = lane >> 4;

  // ---- B init: 32 rows x 2048 K; 16 threads/row ----
  {
    int brow = tid >> 4;          // 0..31
    int sub = tid & 15;
    const float* src = w2 + ((size_t)e * HID + ntb + brow) * FFNDIM;
    int swz = brow & 7;
#pragma unroll
    for (int i = 0; i < 16; ++i) {
      int g = sub + i * 16;       // granule of 8 elems (256 per row)
      float4 a = *reinterpret_cast<const float4*>(src + g * 8);
      float4 b = *reinterpret_cast<const float4*>(src + g * 8 + 4);
      *reinterpret_cast<short8*>(&sB2[brow * 2048 + ((g ^ swz) << 3)]) = pack8(a, b);
    }
  }
  __syncthreads();

  for (int tix = wid; tix * 64 < cnt; tix += 8) {
    const unsigned short* Ab[4];
#pragma unroll
    for (int mf = 0; mf < 4; ++mf) {
      int r = tix * 64 + mf * 16 + fr;
      if (r > cnt - 1) r = cnt - 1;
      Ab[mf] = hbuf + (size_t)(off + r) * FFNDIM + fq * 8;
    }

    f32x4 acc[4][2];
#pragma unroll
    for (int mf = 0; mf < 4; ++mf)
#pragma unroll
      for (int nf = 0; nf < 2; ++nf) acc[mf][nf] = (f32x4){0.f, 0.f, 0.f, 0.f};

    short8 p0[4], p1[4];
#define ALOAD2(P, T)                                                        \
    do {                                                                    \
      _Pragma("unroll")                                                     \
      for (int mf = 0; mf < 4; ++mf)                                        \
        P[mf] = *reinterpret_cast<const short8*>(Ab[mf] + (T) * 32);        \
    } while (0)
#define COMP2(P, T)                                                         \
    do {                                                                    \
      short8 bfr[2];                                                        \
      _Pragma("unroll")                                                     \
      for (int nf = 0; nf < 2; ++nf) {                                      \
        int row = nf * 16 + fr;                                             \
        int g = (T) * 4 + fq;                                               \
        bfr[nf] = *reinterpret_cast<const short8*>(                         \
            &sB2[row * 2048 + ((g ^ (row & 7)) << 3)]);                     \
      }                                                                     \
      __builtin_amdgcn_s_setprio(1);                                        \
      _Pragma("unroll")                                                     \
      for (int mf = 0; mf < 4; ++mf)                                        \
        _Pragma("unroll")                                                   \
        for (int nf = 0; nf < 2; ++nf)                                      \
          acc[mf][nf] = __builtin_amdgcn_mfma_f32_16x16x32_bf16(            \
              P[mf], bfr[nf], acc[mf][nf], 0, 0, 0);                        \
      __builtin_amdgcn_s_setprio(0);                                        \
    } while (0)

    ALOAD2(p0, 0);
    ALOAD2(p1, 1);
    for (int t = 0; t < 64; t += 2) {
      COMP2(p0, t);
      if (t + 2 < 64) ALOAD2(p0, t + 2);
      COMP2(p1, t + 1);
      if (t + 3 < 64) ALOAD2(p1, t + 3);
    }
#undef ALOAD2
#undef COMP2

#pragma unroll
    for (int mf = 0; mf < 4; ++mf) {
      int rl = tix * 64 + mf * 16 + fq * 4;
#pragma unroll
      for (int jj = 0; jj < 4; ++jj) {
        int gm = rl + jj;
        if (gm < cnt) {
#pragma unroll
          for (int nf = 0; nf < 2; ++nf)
            Yg[(size_t)(off + gm) * HID + ntb + nf * 16 + fr] = acc[mf][nf][jj];
        }
      }
    }
  }
}

// ======== combine: out[t] = tw0*Y[r0] + tw1*Y[r1] (single plane) ========
__global__ __launch_bounds__(256) void combine_kernel(
    const float* __restrict__ Yg, const int* __restrict__ tok_rows,
    const float* __restrict__ top_w, float* __restrict__ out) {
  int t = blockIdx.x;
  int c = threadIdx.x * 4;
  int r0 = tok_rows[t * 2 + 0];
  int r1 = tok_rows[t * 2 + 1];
  float tw0 = top_w[t * 2 + 0];
  float tw1 = top_w[t * 2 + 1];
  float4 a0 = *reinterpret_cast<const float4*>(Yg + (size_t)r0 * HID + c);
  float4 a1 = *reinterpret_cast<const float4*>(Yg + (size_t)r1 * HID + c);
  float4 o;
  o.x = tw0 * a0.x + tw1 * a1.x;
  o.y = tw0 * a0.y + tw1 * a1.y;
  o.z = tw0 * a0.z + tw1 * a1.z;
  o.w = tw0 * a0.w + tw1 * a1.w;
  *reinterpret_cast<float4*>(out + (size_t)t * HID + c) = o;
}

extern "C" void kernel_launch(void* const* d_in, const int* in_sizes, int n_in,
                              void* d_out, int out_size, void* d_ws, size_t ws_size,
                              hipStream_t stream) {
  const float* x  = (const float*)d_in[0];
  const float* gw = (const float*)d_in[1];
  const float* w1 = (const float*)d_in[2];
  const float* w3 = (const float*)d_in[3];
  const float* w2 = (const float*)d_in[4];
  float* out = (float*)d_out;

  char* ws = (char*)d_ws;
  int*   counts   = (int*)(ws + 0);
  int*   cursor   = (int*)(ws + 32);
  int*   offsets  = (int*)(ws + 64);
  int*   top_i    = (int*)(ws + 1024);
  float* top_w    = (float*)(ws + 17408);
  int*   row_tok  = (int*)(ws + 33792);
  int*   tok_rows = (int*)(ws + 50176);
  unsigned short* Xg   = (unsigned short*)(ws + 66560);     // 4224*1024 bf16
  unsigned short* hbuf = (unsigned short*)(ws + 8717312);   // 4224*2048 bf16
  float*          Yg   = (float*)(ws + 26018816);           // 4096*1024 f32

  hipFuncSetAttribute((const void*)gemm1_wr,
                      hipFuncAttributeMaxDynamicSharedMemorySize, 131072);
  hipFuncSetAttribute((const void*)gemm2_wr,
                      hipFuncAttributeMaxDynamicSharedMemorySize, 131072);

  hipMemsetAsync(ws, 0, 128, stream);

  router_kernel<<<T_TOK / 4, 256, 0, stream>>>(x, gw, counts, top_i, top_w);
  offsets_kernel<<<1, 64, 0, stream>>>(counts, offsets);
  scatter_kernel<<<(T_TOK + 255) / 256, 256, 0, stream>>>(top_i, top_w, offsets, cursor, row_tok, tok_rows);
  gather_kernel<<<T_TOK * 2, 256, 0, stream>>>(x, row_tok, Xg);

  // gemm1: 64 col-tiles x 8 experts = 512 blocks (128 KB LDS each)
  gemm1_wr<<<dim3(FFNDIM / 32, 1, NEXP), 512, 131072, stream>>>(Xg, w1, w3, counts, offsets, hbuf);
  // gemm2: 32 col-tiles x 8 experts = 256 blocks
  gemm2_wr<<<dim3(HID / 32, 1, NEXP), 512, 131072, stream>>>(hbuf, w2, counts, offsets, Yg);
  combine_kernel<<<T_TOK, 256, 0, stream>>>(Yg, tok_rows, top_w, out);
}